// Round 1
// baseline (1099.573 us; speedup 1.0000x reference)
//
#include <hip/hip_runtime.h>
#include <cstdint>
#include <cstddef>

#define N_NODES 50000
#define N_EDGES 800000
#define D 128
#define DE 16

// ---------------------------------------------------------------------------
// CSR build (dst-sorted, graph j=2, shared by both layers)
// ---------------------------------------------------------------------------
__global__ void csr_hist(const int* __restrict__ dst, int* __restrict__ count){
  int e = blockIdx.x*256 + threadIdx.x;
  if (e < N_EDGES) atomicAdd(&count[dst[e]], 1);
}

__global__ __launch_bounds__(1024) void csr_scan(const int* __restrict__ count,
                                                 int* __restrict__ row_start,
                                                 int* __restrict__ cursor){
  __shared__ int sdata[1024];
  const int CH = 49;                 // 1024*49 = 50176 >= 50001
  int t = threadIdx.x;
  int base_i = t*CH;
  int tot = 0;
  for (int u=0;u<CH;u++){ int i = base_i+u; if (i < N_NODES) tot += count[i]; }
  sdata[t] = tot; __syncthreads();
  for (int off=1; off<1024; off<<=1){
    int v = (t >= off) ? sdata[t-off] : 0;
    __syncthreads();
    sdata[t] += v;
    __syncthreads();
  }
  int run = sdata[t] - tot;          // exclusive base for this chunk
  for (int u=0;u<CH;u++){
    int i = base_i+u;
    if (i <= N_NODES){
      row_start[i] = run;
      if (i < N_NODES){ cursor[i] = run; run += count[i]; }
    }
  }
}

__global__ void csr_scatter(const int* __restrict__ src, const int* __restrict__ dst,
                            int* __restrict__ cursor, int* __restrict__ perm,
                            int* __restrict__ src_perm){
  int e = blockIdx.x*256 + threadIdx.x;
  if (e >= N_EDGES) return;
  int d = dst[e];
  int pos = atomicAdd(&cursor[d], 1);
  perm[pos] = e;
  src_perm[pos] = src[e];
}

// ---------------------------------------------------------------------------
// LSTM: P[t][r] = Wih[r] . x[t] + (bih[r]+bhh[r])   (wide, parallel)
// grid = 256 blocks: (layer i = bid>>7, t = bid&127), 512 threads = rows r
// ---------------------------------------------------------------------------
__global__ __launch_bounds__(512) void lstm_pre(const float* __restrict__ Wih,
     const float* __restrict__ bih, const float* __restrict__ bhh,
     const float* __restrict__ xin, float* __restrict__ P){
  __shared__ float xs[128];
  int i = blockIdx.x >> 7, t = blockIdx.x & 127;
  const float* x = xin + (size_t)i*16384;
  if (threadIdx.x < 128) xs[threadIdx.x] = x[t*128 + threadIdx.x];
  __syncthreads();
  int r = threadIdx.x;
  const float4* wr = (const float4*)(Wih + (size_t)(i*512 + r)*128);
  const float4* x4 = (const float4*)xs;
  float acc = bih[i*512+r] + bhh[i*512+r];
  #pragma unroll
  for (int k=0;k<32;k++){
    float4 w = wr[k]; float4 xv = x4[k];
    acc += w.x*xv.x + w.y*xv.y + w.z*xv.z + w.w*xv.w;
  }
  P[(size_t)(i*128+t)*512 + r] = acc;
}

// One workgroup per layer; Whh row held in 128 VGPRs/thread; recurrent scan.
// gate rows: [0,128)=i  [128,256)=f  [256,384)=g(tanh)  [384,512)=o
__global__ __launch_bounds__(512) void lstm_scan(const float* __restrict__ Whh,
     const float* __restrict__ P, float* __restrict__ xout){
  __shared__ float hs[128];
  __shared__ float gs[512];
  int i = blockIdx.x, r = threadIdx.x;
  float4 wreg[32];
  {
    const float4* wr = (const float4*)(Whh + (size_t)(i*512+r)*128);
    #pragma unroll
    for (int k=0;k<32;k++) wreg[k] = wr[k];
  }
  float c = 0.f;
  if (r < 128) hs[r] = 0.f;
  __syncthreads();
  const float* Pi = P + (size_t)i*128*512;
  for (int t=0;t<128;t++){
    float acc = Pi[t*512 + r];
    const float4* h4 = (const float4*)hs;
    #pragma unroll
    for (int k=0;k<32;k++){
      float4 hv = h4[k]; float4 wv = wreg[k];
      acc += wv.x*hv.x + wv.y*hv.y + wv.z*hv.z + wv.w*hv.w;
    }
    float g;
    if (r < 256 || r >= 384){
      g = 1.f/(1.f + __expf(-acc));           // sigmoid (i,f,o)
    } else {
      float xc = fminf(fmaxf(acc, -15.f), 15.f);
      float e2 = __expf(2.f*xc);
      g = (e2-1.f)/(e2+1.f);                  // tanh (g)
    }
    gs[r] = g;
    __syncthreads();
    if (r < 128){
      c = gs[128+r]*c + gs[r]*gs[256+r];
      float xc = fminf(fmaxf(c, -15.f), 15.f);
      float e2 = __expf(2.f*xc);
      float th = (e2-1.f)/(e2+1.f);
      float h = gs[384+r]*th;
      hs[r] = h;
      xout[(size_t)(i*128+t)*128 + r] = h;
    }
    __syncthreads();
  }
}

// ---------------------------------------------------------------------------
// GAT stage A: ft = f @ W (50000x128 @ 128x128, fp32) + s_src = f @ a_src
// block = 256 threads, 32 nodes/block. W staged in 64-row LDS chunks (<=64KB).
// ---------------------------------------------------------------------------
__global__ __launch_bounds__(256) void gat_transform(const float* __restrict__ f,
    const float* __restrict__ W, const float* __restrict__ aw,
    float* __restrict__ ft, float* __restrict__ s_src){
  __shared__ float Ws[64*128];     // [k2][j] chunk of W rows        (32 KB)
  __shared__ float fs[128*36];     // [k][n] transposed f tile, pad36 (18 KB)
  int n0 = blockIdx.x * 32;
  { // stage fs (transposed)
    int n = threadIdx.x >> 3, kq = threadIdx.x & 7;
    int gn = n0 + n;
    #pragma unroll
    for (int p=0;p<4;p++){
      int k = kq*16 + p*4;
      float4 v = make_float4(0.f,0.f,0.f,0.f);
      if (gn < N_NODES) v = *(const float4*)(f + (size_t)gn*128 + k);
      fs[(k+0)*36+n] = v.x; fs[(k+1)*36+n] = v.y;
      fs[(k+2)*36+n] = v.z; fs[(k+3)*36+n] = v.w;
    }
  }
  int jg = threadIdx.x & 31, ng = threadIdx.x >> 5;  // cols 4*jg.., nodes 4*ng..
  float4 a0=make_float4(0,0,0,0), a1=a0, a2=a0, a3=a0;
  for (int kk=0; kk<128; kk+=64){
    __syncthreads();
    { // stage W rows kk..kk+63
      const float4* W4 = (const float4*)(W + (size_t)kk*128);
      float4* Ws4w = (float4*)Ws;
      for (int idx = threadIdx.x; idx < 2048; idx += 256) Ws4w[idx] = W4[idx];
    }
    __syncthreads();
    const float4* Ws4 = (const float4*)Ws;
    #pragma unroll 4
    for (int k2=0;k2<64;k2++){
      float4 wv = Ws4[k2*32 + jg];
      float4 fv = *(const float4*)&fs[(kk+k2)*36 + (ng<<2)];
      a0.x += fv.x*wv.x; a0.y += fv.x*wv.y; a0.z += fv.x*wv.z; a0.w += fv.x*wv.w;
      a1.x += fv.y*wv.x; a1.y += fv.y*wv.y; a1.z += fv.y*wv.z; a1.w += fv.y*wv.w;
      a2.x += fv.z*wv.x; a2.y += fv.z*wv.y; a2.z += fv.z*wv.z; a2.w += fv.z*wv.w;
      a3.x += fv.w*wv.x; a3.y += fv.w*wv.y; a3.z += fv.w*wv.z; a3.w += fv.w*wv.w;
    }
  }
  int nb = n0 + (ng<<2);
  if (nb+0 < N_NODES) *(float4*)(ft + (size_t)(nb+0)*128 + (jg<<2)) = a0;
  if (nb+1 < N_NODES) *(float4*)(ft + (size_t)(nb+1)*128 + (jg<<2)) = a1;
  if (nb+2 < N_NODES) *(float4*)(ft + (size_t)(nb+2)*128 + (jg<<2)) = a2;
  if (nb+3 < N_NODES) *(float4*)(ft + (size_t)(nb+3)*128 + (jg<<2)) = a3;
  // s_src for this block's nodes (fs still valid; a_dst cancels in softmax)
  if (threadIdx.x < 32){
    int gn = n0 + threadIdx.x;
    if (gn < N_NODES){
      float s = 0.f;
      for (int k=0;k<128;k++) s += fs[k*36 + threadIdx.x] * aw[k];
      s_src[gn] = s;
    }
  }
}

// ---------------------------------------------------------------------------
// GAT stage B: score[p] = s_src[src_perm[p]] + ef[perm[p]] . a_edge
// (s_dst[dst] dropped: constant per softmax segment -> cancels)
// ---------------------------------------------------------------------------
__global__ __launch_bounds__(256) void gat_edge_score(const int* __restrict__ perm,
    const int* __restrict__ src_perm, const float* __restrict__ s_src,
    const float* __restrict__ ef, const float* __restrict__ aw,
    float* __restrict__ score){
  int p = blockIdx.x*256 + threadIdx.x;
  if (p >= N_EDGES) return;
  int e = perm[p];
  int s = src_perm[p];
  const float4* A = (const float4*)(aw + 128);
  float4 A0=A[0], A1=A[1], A2=A[2], A3=A[3];
  const float4* ev = (const float4*)(ef + (size_t)e*16);
  float4 v0=ev[0], v1=ev[1], v2=ev[2], v3=ev[3];
  float acc = s_src[s];
  acc += v0.x*A0.x + v0.y*A0.y + v0.z*A0.z + v0.w*A0.w;
  acc += v1.x*A1.x + v1.y*A1.y + v1.z*A1.z + v1.w*A1.w;
  acc += v2.x*A2.x + v2.y*A2.y + v2.z*A2.z + v2.w*A2.w;
  acc += v3.x*A3.x + v3.y*A3.y + v3.z*A3.z + v3.w*A3.w;
  score[p] = acc;
}

// ---------------------------------------------------------------------------
// GAT stage C: per-node softmax + alpha-weighted gather of ft + leaky_relu
// one wave (64 lanes) per node; 2 feature cols per lane
// ---------------------------------------------------------------------------
__global__ __launch_bounds__(256) void gat_aggregate(const int* __restrict__ row_start,
    const int* __restrict__ src_perm, const float* __restrict__ score,
    const float* __restrict__ ft, float* __restrict__ out){
  int lane = threadIdx.x & 63;
  int wv = threadIdx.x >> 6;
  int n = blockIdx.x*4 + wv;
  if (n >= N_NODES) return;
  int s = row_start[n], e = row_start[n+1];
  float m = -1e30f;
  for (int p = s+lane; p < e; p += 64) m = fmaxf(m, score[p]);
  #pragma unroll
  for (int off=32; off; off>>=1) m = fmaxf(m, __shfl_xor(m, off));
  float den = 0.f;
  for (int p = s+lane; p < e; p += 64) den += __expf(score[p]-m);
  #pragma unroll
  for (int off=32; off; off>>=1) den += __shfl_xor(den, off);
  float inv = (den > 0.f) ? 1.f/den : 0.f;
  float a0 = 0.f, a1 = 0.f;
  for (int p = s; p < e; p++){
    float al = __expf(score[p]-m)*inv;
    int sp = src_perm[p];
    float2 v = ((const float2*)(ft + (size_t)sp*128))[lane];
    a0 += al*v.x; a1 += al*v.y;
  }
  float2 o;
  o.x = (a0 > 0.f) ? a0 : 0.01f*a0;
  o.y = (a1 > 0.f) ? a1 : 0.01f*a1;
  ((float2*)(out + (size_t)n*128))[lane] = o;
}

// ---------------------------------------------------------------------------
extern "C" void kernel_launch(void* const* d_in, const int* in_sizes, int n_in,
                              void* d_out, int out_size, void* d_ws, size_t ws_size,
                              hipStream_t stream){
  (void)in_sizes; (void)n_in; (void)out_size; (void)ws_size;
  const int*   src     = (const int*)d_in[0] + (size_t)2*N_EDGES;       // j=2 slice
  const int*   dst     = (const int*)d_in[1] + (size_t)2*N_EDGES;
  const float* n_feats = (const float*)d_in[2] + (size_t)2*N_NODES*D;
  const float* e_feats = (const float*)d_in[3] + (size_t)2*N_EDGES*DE;
  const float* W0      = (const float*)d_in[4];
  const float* Wih     = (const float*)d_in[5];
  const float* Whh     = (const float*)d_in[6];
  const float* bih     = (const float*)d_in[7];
  const float* bhh     = (const float*)d_in[8];
  const float* a_w     = (const float*)d_in[9];
  float* out = (float*)d_out;

  char* wsp = (char*)d_ws;
  auto alloc = [&](size_t bytes)->char*{
    char* p = wsp; wsp += (bytes + 255) & ~(size_t)255; return p;
  };
  float* P         = (float*)alloc((size_t)2*128*512*4);
  float* xA        = (float*)alloc((size_t)2*128*128*4);
  float* xB        = (float*)alloc((size_t)2*128*128*4);
  int*   count     = (int*)  alloc((size_t)N_NODES*4);
  int*   row_start = (int*)  alloc((size_t)(N_NODES+1)*4);
  int*   cursor    = (int*)  alloc((size_t)N_NODES*4);
  int*   perm      = (int*)  alloc((size_t)N_EDGES*4);
  int*   src_perm  = (int*)  alloc((size_t)N_EDGES*4);
  float* score     = (float*)alloc((size_t)N_EDGES*4);
  float* s_src     = (float*)alloc((size_t)N_NODES*4);
  float* ft        = (float*)alloc((size_t)N_NODES*D*4);
  float* f1        = (float*)alloc((size_t)N_NODES*D*4);

  // CSR build (once; same graph for both layers)
  hipMemsetAsync(count, 0, (size_t)N_NODES*4, stream);
  csr_hist   <<<(N_EDGES+255)/256, 256, 0, stream>>>(dst, count);
  csr_scan   <<<1, 1024, 0, stream>>>(count, row_start, cursor);
  csr_scatter<<<(N_EDGES+255)/256, 256, 0, stream>>>(src, dst, cursor, perm, src_perm);

  // LSTM: 3 applications, both layers batched per launch; final W lands in xA
  const float* xi = W0;
  float* xo = xA;
  for (int app=0; app<3; app++){
    lstm_pre <<<256, 512, 0, stream>>>(Wih, bih, bhh, xi, P);
    lstm_scan<<<2,   512, 0, stream>>>(Whh, P, xo);
    xi = xo;
    xo = (app==0) ? xB : xA;
  }
  const float* Wfin = xA;   // app0->xA, app1->xB, app2->xA

  // Two GAT layers on graph j=2 (feats[0],feats[1] are dead w.r.t. output)
  const float* fin = n_feats;
  for (int l=0; l<2; l++){
    float* outl = (l==0) ? f1 : out;
    gat_transform <<<(N_NODES+31)/32, 256, 0, stream>>>(fin, Wfin + (size_t)l*16384,
                                                        a_w + (size_t)l*272, ft, s_src);
    gat_edge_score<<<(N_EDGES+255)/256, 256, 0, stream>>>(perm, src_perm, s_src,
                                                          e_feats, a_w + (size_t)l*272, score);
    gat_aggregate <<<N_NODES/4, 256, 0, stream>>>(row_start, src_perm, score, ft, outl);
    fin = f1;
  }
}